// Round 2
// baseline (1234.531 us; speedup 1.0000x reference)
//
#include <hip/hip_runtime.h>
#include <hip/hip_bf16.h>
#include <stdint.h>

#define MODEL_DIM 4096
#define HEAD_DIM  128
#define NH        32
#define NKV       8
#define BB        2
#define SS        2048
#define ROWS      (BB*SS)                        // 4096
#define QKVN      (MODEL_DIM + 2*NKV*HEAD_DIM)   // 6144
#define KOFF      MODEL_DIM                      // 4096
#define VOFF      (MODEL_DIM + NKV*HEAD_DIM)     // 5120
#define SCALE_QK  0.08838834764831845f           // 1/sqrt(128)

typedef __attribute__((ext_vector_type(8))) short short8;
typedef __attribute__((ext_vector_type(4))) float f32x4;

static __device__ __forceinline__ unsigned short f2bf(float f) {
  union { float f; unsigned u; } v; v.f = f;
  unsigned r = v.u + 0x7fffu + ((v.u >> 16) & 1u);   // round-to-nearest-even
  return (unsigned short)(r >> 16);
}
static __device__ __forceinline__ float bf2f(unsigned short u) {
  union { unsigned u; float f; } v; v.u = ((unsigned)u) << 16;
  return v.f;
}

// ---------------------------------------------------------------- converts
__global__ void cvt_bf16(const float* __restrict__ s, unsigned short* __restrict__ d, int n4) {
  int i = blockIdx.x * blockDim.x + threadIdx.x;
  int st = gridDim.x * blockDim.x;
  for (; i < n4; i += st) {
    float4 v = reinterpret_cast<const float4*>(s)[i];
    ushort4 o;
    o.x = f2bf(v.x); o.y = f2bf(v.y); o.z = f2bf(v.z); o.w = f2bf(v.w);
    reinterpret_cast<ushort4*>(d)[i] = o;
  }
}

// ---------------------------------------------------------------- GEMM  C = A * B^T
// A [M][K] bf16, B [N][K] bf16 (row-major, stride K), C [M][N] (bf16 or f32).
// m97 structure: 128x128 tile, BK=32, 4 waves (2x2), global_load_lds width 16.
template<int OUT_F32>
__global__ __launch_bounds__(256) void gemm_bt(
    const unsigned short* __restrict__ A, const unsigned short* __restrict__ B,
    void* __restrict__ Cv, int M, int N, int K)
{
  __shared__ unsigned short As[128 * 32];
  __shared__ unsigned short Bs[128 * 32];
  const int tid  = threadIdx.x;
  const int lane = tid & 63;
  const int w    = tid >> 6;

  // XCD-bijective swizzle (grids here are always % 8 == 0)
  const int nwg = gridDim.x;
  const int bid = blockIdx.x;
  const int q8  = nwg >> 3;
  const int wg  = (bid & 7) * q8 + (bid >> 3);
  const int gm  = M >> 7;
  const int bm  = wg % gm, bn = wg / gm;
  const int m0  = bm << 7, n0 = bn << 7;
  const int wm  = (w >> 1) << 6, wn = (w & 1) << 6;

  f32x4 acc[4][4] = {};

  const int rowA = lane >> 2;          // 16 rows per wave per issue
  const int ch8  = (lane & 3) * 8;     // 4 chunks of 8 bf16 per row

  for (int k0 = 0; k0 < K; k0 += 32) {
    __syncthreads();                   // previous iteration's LDS reads done
    #pragma unroll
    for (int i = 0; i < 2; ++i) {
      const unsigned short* ga = A + (size_t)(m0 + i*64 + w*16 + rowA) * K + k0 + ch8;
      __builtin_amdgcn_global_load_lds((const __attribute__((address_space(1))) void*)ga,
          (__attribute__((address_space(3))) void*)&As[(i*64 + w*16) * 32], 16, 0, 0);
      const unsigned short* gb = B + (size_t)(n0 + i*64 + w*16 + rowA) * K + k0 + ch8;
      __builtin_amdgcn_global_load_lds((const __attribute__((address_space(1))) void*)gb,
          (__attribute__((address_space(3))) void*)&Bs[(i*64 + w*16) * 32], 16, 0, 0);
    }
    __syncthreads();                   // compiler drains vmcnt(0) before barrier

    short8 af[4], bf[4];
    const int fr = lane & 15, fg = lane >> 4;
    #pragma unroll
    for (int r = 0; r < 4; ++r)
      af[r] = *(const short8*)&As[(wm + r*16 + fr) * 32 + fg * 8];
    #pragma unroll
    for (int r = 0; r < 4; ++r)
      bf[r] = *(const short8*)&Bs[(wn + r*16 + fr) * 32 + fg * 8];
    #pragma unroll
    for (int i = 0; i < 4; ++i)
      #pragma unroll
      for (int j = 0; j < 4; ++j)
        acc[i][j] = __builtin_amdgcn_mfma_f32_16x16x32_bf16(af[i], bf[j], acc[i][j], 0, 0, 0);
  }

  // C/D layout (m89-verified): col = lane&15, row = (lane>>4)*4 + e
  const int cr = (lane >> 4) * 4, cc = lane & 15;
  #pragma unroll
  for (int i = 0; i < 4; ++i)
    #pragma unroll
    for (int j = 0; j < 4; ++j) {
      const int gr = m0 + wm + i*16 + cr;
      const int gc = n0 + wn + j*16 + cc;
      #pragma unroll
      for (int e = 0; e < 4; ++e) {
        const float v = acc[i][j][e];
        if (OUT_F32) ((float*)Cv)[(size_t)(gr + e) * N + gc] = v;
        else ((unsigned short*)Cv)[(size_t)(gr + e) * N + gc] = f2bf(v);
      }
    }
}

// ---------------------------------------------------------------- RoPE (in-place on fused QKV, Q + K parts)
__global__ void rope_kernel(unsigned short* __restrict__ qkv, const int* __restrict__ posp) {
  const int row = blockIdx.x;                       // 0..4095 = b*2048 + s
  const float t = (float)((row & (SS - 1)) + posp[0]);
  const float c0 = -13.28771237954945f / 64.0f;     // -log2(10000)/64
  for (int i = threadIdx.x; i < (NH + NKV) * 64; i += blockDim.x) {
    const int hh = i >> 6, p = i & 63;
    const int colbase = (hh < NH) ? hh * HEAD_DIM : KOFF + (hh - NH) * HEAD_DIM;
    const float inv = exp2f((float)p * c0);
    float sn, cs;
    sincosf(t * inv, &sn, &cs);
    const size_t base = (size_t)row * QKVN + colbase + 2 * p;
    const float x1 = bf2f(qkv[base]), x2 = bf2f(qkv[base + 1]);
    qkv[base]     = f2bf(x1 * cs - x2 * sn);
    qkv[base + 1] = f2bf(x1 * sn + x2 * cs);
  }
}

// ---------------------------------------------------------------- flash attention (causal, GQA 4:1)
#define QBLK 64
#define KVB  64
#define LDK  136   // 64 rows of K, padded (2-way bank alias = free)
#define LDV  140   // 64 rows of V, padded for scalar-transposed reads
#define LDP  72    // per-wave 16-row P tile

static __device__ __forceinline__ float bcast_row16(float v0, float v1, float v2, float v3, int lane) {
  // input: lanes in group g=(lane>>4) hold values for rows 4g+i (i=0..3)
  // output: each lane receives value for row q = lane&15
  const int sel = (lane >> 2) & 3;
  const float a = (sel & 1) ? v1 : v0;
  const float b = (sel & 1) ? v3 : v2;
  const float m = (sel & 2) ? b : a;
  const int q = lane & 15;
  return __shfl(m, ((q >> 2) << 4) + ((q & 3) << 2));
}

__global__ __launch_bounds__(256) void attn_kernel(
    const unsigned short* __restrict__ qkv, unsigned short* __restrict__ out)
{
  __shared__ unsigned short Ks[KVB * LDK];
  __shared__ unsigned short Vs[KVB * LDV];
  __shared__ unsigned short Ps[4 * 16 * LDP];

  const int tid  = threadIdx.x;
  const int lane = tid & 63;
  const int w    = tid >> 6;
  const int bh   = blockIdx.y;            // b*32 + h
  const int b    = bh >> 5, h = bh & 31;
  const int kvh  = h >> 2;
  const int q0   = blockIdx.x * QBLK;
  const int fr   = lane & 15, fg = lane >> 4;

  // Q fragments for this wave's 16 rows (A-operand: row=lane&15, k=(lane>>4)*8+i)
  const size_t qrow0 = (size_t)(b * SS + q0 + w * 16);
  short8 qf[4];
  #pragma unroll
  for (int kk = 0; kk < 4; ++kk)
    qf[kk] = *(const short8*)&qkv[(qrow0 + fr) * QKVN + h * HEAD_DIM + kk * 32 + fg * 8];

  f32x4 ot[8] = {};                       // O^T tiles: col=q(lane&15), row=d-within-tile
  float m_run[4], l_run[4];
  #pragma unroll
  for (int i = 0; i < 4; ++i) { m_run[i] = -INFINITY; l_run[i] = 0.f; }

  const int ntile = (q0 >> 6) + 1;
  for (int jt = 0; jt < ntile; ++jt) {
    const int j0 = jt * KVB;
    const bool diag = (jt == ntile - 1);
    __syncthreads();
    // stage K (linear, padded) and V (linear, padded) — coalesced 16B chunks
    #pragma unroll
    for (int it = 0; it < 4; ++it) {
      const int cid = it * 256 + tid;          // 1024 chunks of 8 bf16
      const int row = cid >> 4, c8 = (cid & 15) << 3;
      const size_t grow = (size_t)(b * SS + j0 + row);
      *(uint4*)&Ks[row * LDK + c8] = *(const uint4*)&qkv[grow * QKVN + KOFF + kvh * HEAD_DIM + c8];
      const uint4 vv = *(const uint4*)&qkv[grow * QKVN + VOFF + kvh * HEAD_DIM + c8];
      *(uint2*)&Vs[row * LDV + c8]     = make_uint2(vv.x, vv.y);
      *(uint2*)&Vs[row * LDV + c8 + 4] = make_uint2(vv.z, vv.w);
    }
    __syncthreads();

    // QK^T: 4 col-tiles of 16 kv each; scores layout row=fg*4+i (q), col=fr (kv)
    float pv[4][4];
    #pragma unroll
    for (int ct = 0; ct < 4; ++ct) {
      f32x4 s = {};
      #pragma unroll
      for (int kk = 0; kk < 4; ++kk) {
        const short8 kf = *(const short8*)&Ks[(ct * 16 + fr) * LDK + kk * 32 + fg * 8];
        s = __builtin_amdgcn_mfma_f32_16x16x32_bf16(qf[kk], kf, s, 0, 0, 0);
      }
      #pragma unroll
      for (int i = 0; i < 4; ++i) {
        float v = s[i] * SCALE_QK;
        if (diag) {
          const int qr = w * 16 + fg * 4 + i;      // row within q-block
          const int kc = ct * 16 + fr;             // col within kv tile (j0==q0)
          if (kc > qr) v = -INFINITY;
        }
        pv[ct][i] = v;
      }
    }

    // online softmax (per wave-row; 16-lane-group shfl reductions)
    float resc[4];
    #pragma unroll
    for (int i = 0; i < 4; ++i) {
      float mx = fmaxf(fmaxf(pv[0][i], pv[1][i]), fmaxf(pv[2][i], pv[3][i]));
      #pragma unroll
      for (int d = 1; d < 16; d <<= 1) mx = fmaxf(mx, __shfl_xor(mx, d));
      const float nm = fmaxf(m_run[i], mx);
      resc[i] = expf(m_run[i] - nm);
      m_run[i] = nm;
      float sum = 0.f;
      #pragma unroll
      for (int ct = 0; ct < 4; ++ct) {
        const float e = expf(pv[ct][i] - nm);
        pv[ct][i] = e;
        sum += e;
      }
      #pragma unroll
      for (int d = 1; d < 16; d <<= 1) sum += __shfl_xor(sum, d);
      l_run[i] = l_run[i] * resc[i] + sum;
    }

    // P -> LDS (bf16), per-wave region; same-wave RAW ordered by lgkmcnt
    unsigned short* Pw = &Ps[w * 16 * LDP];
    #pragma unroll
    for (int ct = 0; ct < 4; ++ct)
      #pragma unroll
      for (int i = 0; i < 4; ++i)
        Pw[(fg * 4 + i) * LDP + ct * 16 + fr] = f2bf(pv[ct][i]);

    // rescale O^T (per-lane q = lane&15)
    const float rq = bcast_row16(resc[0], resc[1], resc[2], resc[3], lane);
    #pragma unroll
    for (int oc = 0; oc < 8; ++oc)
      #pragma unroll
      for (int e = 0; e < 4; ++e) ot[oc][e] *= rq;

    // PV (swapped): O^T[d][q] += V^T[d][kv] * P^T[kv][q]
    #pragma unroll
    for (int kk2 = 0; kk2 < 2; ++kk2) {
      const short8 pf = *(const short8*)&Pw[fr * LDP + kk2 * 32 + fg * 8];
      #pragma unroll
      for (int oc = 0; oc < 8; ++oc) {
        short8 vf;
        #pragma unroll
        for (int e = 0; e < 8; ++e)
          vf[e] = (short)Vs[(kk2 * 32 + fg * 8 + e) * LDV + oc * 16 + fr];
        ot[oc] = __builtin_amdgcn_mfma_f32_16x16x32_bf16(vf, pf, ot[oc], 0, 0, 0);
      }
    }
  }

  // epilogue: divide by l (per q), store O (lane holds 4 consecutive d per tile)
  const float invq = bcast_row16(1.f / l_run[0], 1.f / l_run[1],
                                 1.f / l_run[2], 1.f / l_run[3], lane);
  const size_t orow = (size_t)(b * SS + q0 + w * 16) + (lane & 15);
  #pragma unroll
  for (int oc = 0; oc < 8; ++oc) {
    const unsigned short e0 = f2bf(ot[oc][0] * invq);
    const unsigned short e1 = f2bf(ot[oc][1] * invq);
    const unsigned short e2 = f2bf(ot[oc][2] * invq);
    const unsigned short e3 = f2bf(ot[oc][3] * invq);
    const uint2 val = make_uint2((unsigned)e0 | ((unsigned)e1 << 16),
                                 (unsigned)e2 | ((unsigned)e3 << 16));
    *(uint2*)&out[orow * MODEL_DIM + h * HEAD_DIM + oc * 16 + fg * 4] = val;
  }
}

// ---------------------------------------------------------------- launch
extern "C" void kernel_launch(void* const* d_in, const int* in_sizes, int n_in,
                              void* d_out, int out_size, void* d_ws, size_t ws_size,
                              hipStream_t stream) {
  const float* x  = (const float*)d_in[0];
  const float* wq = (const float*)d_in[1];
  const float* wk = (const float*)d_in[2];
  const float* wv = (const float*)d_in[3];
  const float* wo = (const float*)d_in[4];
  const int* pos  = (const int*)d_in[6];        // mask (d_in[5]) unused: causal computed in-kernel
  float* out = (float*)d_out;

  // workspace layout (bf16 elements), total ≈ 202 MB
  unsigned short* xb   = (unsigned short*)d_ws;
  unsigned short* wqkv = xb   + (size_t)ROWS * MODEL_DIM;
  unsigned short* wob  = wqkv + (size_t)QKVN * MODEL_DIM;
  unsigned short* qkv  = wob  + (size_t)MODEL_DIM * MODEL_DIM;
  unsigned short* attn = qkv  + (size_t)ROWS * QKVN;

  cvt_bf16<<<2048, 256, 0, stream>>>(x,  xb,   ROWS * MODEL_DIM / 4);
  cvt_bf16<<<2048, 256, 0, stream>>>(wq, wqkv, MODEL_DIM * MODEL_DIM / 4);
  cvt_bf16<<<1024, 256, 0, stream>>>(wk, wqkv + (size_t)MODEL_DIM * MODEL_DIM,          NKV * HEAD_DIM * MODEL_DIM / 4);
  cvt_bf16<<<1024, 256, 0, stream>>>(wv, wqkv + (size_t)(MODEL_DIM + NKV * HEAD_DIM) * MODEL_DIM, NKV * HEAD_DIM * MODEL_DIM / 4);
  cvt_bf16<<<2048, 256, 0, stream>>>(wo, wob,  MODEL_DIM * MODEL_DIM / 4);

  gemm_bt<0><<<dim3((ROWS / 128) * (QKVN / 128)), 256, 0, stream>>>(xb, wqkv, qkv, ROWS, QKVN, MODEL_DIM);
  rope_kernel<<<ROWS, 256, 0, stream>>>(qkv, pos);
  attn_kernel<<<dim3(SS / QBLK, BB * NH), 256, 0, stream>>>(qkv, attn);
  gemm_bt<1><<<dim3((ROWS / 128) * (MODEL_DIM / 128)), 256, 0, stream>>>(attn, wob, out, ROWS, MODEL_DIM, MODEL_DIM);
}

// Round 3
// 1157.187 us; speedup vs baseline: 1.0668x; 1.0668x over previous
//
#include <hip/hip_runtime.h>
#include <hip/hip_bf16.h>
#include <stdint.h>

#define MODEL_DIM 4096
#define HEAD_DIM  128
#define NH        32
#define NKV       8
#define BB        2
#define SS        2048
#define ROWS      (BB*SS)                        // 4096
#define QKVN      (MODEL_DIM + 2*NKV*HEAD_DIM)   // 6144
#define KOFF      MODEL_DIM                      // 4096
#define VOFF      (MODEL_DIM + NKV*HEAD_DIM)     // 5120
#define SCALE_QK  0.08838834764831845f           // 1/sqrt(128)

typedef __attribute__((ext_vector_type(8))) short short8;
typedef __attribute__((ext_vector_type(4))) float f32x4;

static __device__ __forceinline__ unsigned short f2bf(float f) {
  union { float f; unsigned u; } v; v.f = f;
  unsigned r = v.u + 0x7fffu + ((v.u >> 16) & 1u);   // round-to-nearest-even
  return (unsigned short)(r >> 16);
}
static __device__ __forceinline__ float bf2f(unsigned short u) {
  union { unsigned u; float f; } v; v.u = ((unsigned)u) << 16;
  return v.f;
}

// ---------------------------------------------------------------- converts
__global__ void cvt_bf16(const float* __restrict__ s, unsigned short* __restrict__ d, int n4) {
  int i = blockIdx.x * blockDim.x + threadIdx.x;
  int st = gridDim.x * blockDim.x;
  for (; i < n4; i += st) {
    float4 v = reinterpret_cast<const float4*>(s)[i];
    ushort4 o;
    o.x = f2bf(v.x); o.y = f2bf(v.y); o.z = f2bf(v.z); o.w = f2bf(v.w);
    reinterpret_cast<ushort4*>(d)[i] = o;
  }
}

// ---------------------------------------------------------------- GEMM  C = A * B^T
// A [M][K] bf16, B [N][K] bf16 (row-major, stride K), C [M][N] (bf16 or f32).
// m97 structure: 128x128 tile, BK=32, 4 waves (2x2), global_load_lds width 16.
template<int OUT_F32>
__global__ __launch_bounds__(256) void gemm_bt(
    const unsigned short* __restrict__ A, const unsigned short* __restrict__ B,
    void* __restrict__ Cv, int M, int N, int K)
{
  __shared__ unsigned short As[128 * 32];
  __shared__ unsigned short Bs[128 * 32];
  const int tid  = threadIdx.x;
  const int lane = tid & 63;
  const int w    = tid >> 6;

  // XCD-bijective swizzle (grids here are always % 8 == 0)
  const int nwg = gridDim.x;
  const int bid = blockIdx.x;
  const int q8  = nwg >> 3;
  const int wg  = (bid & 7) * q8 + (bid >> 3);
  const int gm  = M >> 7;
  const int bm  = wg % gm, bn = wg / gm;
  const int m0  = bm << 7, n0 = bn << 7;
  const int wm  = (w >> 1) << 6, wn = (w & 1) << 6;

  f32x4 acc[4][4] = {};

  const int rowA = lane >> 2;          // 16 rows per wave per issue
  const int ch8  = (lane & 3) * 8;     // 4 chunks of 8 bf16 per row

  for (int k0 = 0; k0 < K; k0 += 32) {
    __syncthreads();                   // previous iteration's LDS reads done
    #pragma unroll
    for (int i = 0; i < 2; ++i) {
      const unsigned short* ga = A + (size_t)(m0 + i*64 + w*16 + rowA) * K + k0 + ch8;
      __builtin_amdgcn_global_load_lds((const __attribute__((address_space(1))) void*)ga,
          (__attribute__((address_space(3))) void*)&As[(i*64 + w*16) * 32], 16, 0, 0);
      const unsigned short* gb = B + (size_t)(n0 + i*64 + w*16 + rowA) * K + k0 + ch8;
      __builtin_amdgcn_global_load_lds((const __attribute__((address_space(1))) void*)gb,
          (__attribute__((address_space(3))) void*)&Bs[(i*64 + w*16) * 32], 16, 0, 0);
    }
    __syncthreads();                   // compiler drains vmcnt(0) before barrier

    short8 af[4], bf[4];
    const int fr = lane & 15, fg = lane >> 4;
    #pragma unroll
    for (int r = 0; r < 4; ++r)
      af[r] = *(const short8*)&As[(wm + r*16 + fr) * 32 + fg * 8];
    #pragma unroll
    for (int r = 0; r < 4; ++r)
      bf[r] = *(const short8*)&Bs[(wn + r*16 + fr) * 32 + fg * 8];
    #pragma unroll
    for (int i = 0; i < 4; ++i)
      #pragma unroll
      for (int j = 0; j < 4; ++j)
        acc[i][j] = __builtin_amdgcn_mfma_f32_16x16x32_bf16(af[i], bf[j], acc[i][j], 0, 0, 0);
  }

  // C/D layout (m89-verified): col = lane&15, row = (lane>>4)*4 + e
  const int cr = (lane >> 4) * 4, cc = lane & 15;
  #pragma unroll
  for (int i = 0; i < 4; ++i)
    #pragma unroll
    for (int j = 0; j < 4; ++j) {
      const int gr = m0 + wm + i*16 + cr;
      const int gc = n0 + wn + j*16 + cc;
      #pragma unroll
      for (int e = 0; e < 4; ++e) {
        const float v = acc[i][j][e];
        if (OUT_F32) ((float*)Cv)[(size_t)(gr + e) * N + gc] = v;
        else ((unsigned short*)Cv)[(size_t)(gr + e) * N + gc] = f2bf(v);
      }
    }
}

// ---------------------------------------------------------------- RoPE (in-place on fused QKV, Q + K parts)
__global__ void rope_kernel(unsigned short* __restrict__ qkv, const int* __restrict__ posp) {
  const int row = blockIdx.x;                       // 0..4095 = b*2048 + s
  const float t = (float)((row & (SS - 1)) + posp[0]);
  const float c0 = -13.28771237954945f / 64.0f;     // -log2(10000)/64
  for (int i = threadIdx.x; i < (NH + NKV) * 64; i += blockDim.x) {
    const int hh = i >> 6, p = i & 63;
    const int colbase = (hh < NH) ? hh * HEAD_DIM : KOFF + (hh - NH) * HEAD_DIM;
    const float inv = exp2f((float)p * c0);
    float sn, cs;
    sincosf(t * inv, &sn, &cs);
    const size_t base = (size_t)row * QKVN + colbase + 2 * p;
    const float x1 = bf2f(qkv[base]), x2 = bf2f(qkv[base + 1]);
    qkv[base]     = f2bf(x1 * cs - x2 * sn);
    qkv[base + 1] = f2bf(x1 * sn + x2 * cs);
  }
}

// ---------------------------------------------------------------- flash attention (causal, GQA 4:1)
#define QBLK 64
#define KVB  64
#define LDK  136   // K rows padded: stride 272B rotates banks per row (read-safe, write-safe)
#define LDP  72    // per-wave 16-row P tile

// V^T tile: Vt[d=128][kv=64], XOR-swizzled at 16B granularity.
//   byte-in-row ^= ((d&7) ^ ((d>>3)&7)) << 4
// (d>>3) term: staging writes (per-instr d = 8*lane+e) land on 8 distinct bank-quads.
// (d&7)  term: PV fragment reads (per-instr d = oc*16+fr) land on 8 distinct bank-quads.
// XOR at 16B granularity keeps aligned short8 reads contiguous (rule #21: same involution
// on write and read side).
static __device__ __forceinline__ int vt_off(int d, int kv) {
  const int byte = (kv << 1) ^ ((((d & 7) ^ ((d >> 3) & 7))) << 4);
  return (d << 6) + (byte >> 1);
}

static __device__ __forceinline__ float bcast_row16(float v0, float v1, float v2, float v3, int lane) {
  // input: lanes in group g=(lane>>4) hold values for rows 4g+i (i=0..3)
  // output: each lane receives value for row q = lane&15
  const int sel = (lane >> 2) & 3;
  const float a = (sel & 1) ? v1 : v0;
  const float b = (sel & 1) ? v3 : v2;
  const float m = (sel & 2) ? b : a;
  const int q = lane & 15;
  return __shfl(m, ((q >> 2) << 4) + ((q & 3) << 2));
}

__global__ __launch_bounds__(256) void attn_kernel(
    const unsigned short* __restrict__ qkv, unsigned short* __restrict__ out)
{
  __shared__ unsigned short Ks[KVB * LDK];     // 17408 B
  __shared__ unsigned short Vt[HEAD_DIM * KVB]; // 16384 B, swizzled V^T
  __shared__ unsigned short Ps[4 * 16 * LDP];  //  9216 B

  const int tid  = threadIdx.x;
  const int lane = tid & 63;
  const int w    = tid >> 6;
  const int bh   = blockIdx.y;            // b*32 + h
  const int b    = bh >> 5, h = bh & 31;
  const int kvh  = h >> 2;
  // reversed launch order: heaviest (most KV tiles) q-blocks first
  const int q0   = (gridDim.x - 1 - blockIdx.x) * QBLK;
  const int fr   = lane & 15, fg = lane >> 4;

  // Q fragments for this wave's 16 rows (A-operand: row=lane&15, k=(lane>>4)*8+i)
  const size_t qrow0 = (size_t)(b * SS + q0 + w * 16);
  short8 qf[4];
  #pragma unroll
  for (int kk = 0; kk < 4; ++kk)
    qf[kk] = *(const short8*)&qkv[(qrow0 + fr) * QKVN + h * HEAD_DIM + kk * 32 + fg * 8];

  f32x4 ot[8] = {};                       // O^T tiles: col=q(lane&15), row=d-within-tile
  float m_run[4], l_run[4];
  #pragma unroll
  for (int i = 0; i < 4; ++i) { m_run[i] = -INFINITY; l_run[i] = 0.f; }

  const int ntile = (q0 >> 6) + 1;
  for (int jt = 0; jt < ntile; ++jt) {
    const int j0 = jt * KVB;
    const bool diag = (jt == ntile - 1);
    __syncthreads();
    // stage K (row-major, padded) and V^T (swizzled) — K: coalesced 16B LDS writes;
    // V: 8 scalar b16 writes per 16B global load, spread by the (d>>3) swizzle term
    #pragma unroll
    for (int it = 0; it < 4; ++it) {
      const int cid = it * 256 + tid;          // 1024 chunks of 8 bf16
      const int row = cid >> 4, c8 = (cid & 15) << 3;
      const size_t grow = (size_t)(b * SS + j0 + row);
      *(uint4*)&Ks[row * LDK + c8] = *(const uint4*)&qkv[grow * QKVN + KOFF + kvh * HEAD_DIM + c8];
      uint4 vv = *(const uint4*)&qkv[grow * QKVN + VOFF + kvh * HEAD_DIM + c8];
      const unsigned short* v8 = (const unsigned short*)&vv;
      #pragma unroll
      for (int e = 0; e < 8; ++e)
        Vt[vt_off(c8 + e, row)] = v8[e];
    }
    __syncthreads();

    // QK^T: 4 col-tiles of 16 kv each; scores layout row=fg*4+i (q), col=fr (kv)
    float pv[4][4];
    #pragma unroll
    for (int ct = 0; ct < 4; ++ct) {
      f32x4 s = {};
      #pragma unroll
      for (int kk = 0; kk < 4; ++kk) {
        const short8 kf = *(const short8*)&Ks[(ct * 16 + fr) * LDK + kk * 32 + fg * 8];
        s = __builtin_amdgcn_mfma_f32_16x16x32_bf16(qf[kk], kf, s, 0, 0, 0);
      }
      #pragma unroll
      for (int i = 0; i < 4; ++i) {
        float v = s[i] * SCALE_QK;
        if (diag) {
          const int qr = w * 16 + fg * 4 + i;      // row within q-block
          const int kc = ct * 16 + fr;             // col within kv tile (j0==q0)
          if (kc > qr) v = -INFINITY;
        }
        pv[ct][i] = v;
      }
    }

    // online softmax (per wave-row; 16-lane-group shfl reductions)
    float resc[4];
    #pragma unroll
    for (int i = 0; i < 4; ++i) {
      float mx = fmaxf(fmaxf(pv[0][i], pv[1][i]), fmaxf(pv[2][i], pv[3][i]));
      #pragma unroll
      for (int d = 1; d < 16; d <<= 1) mx = fmaxf(mx, __shfl_xor(mx, d));
      const float nm = fmaxf(m_run[i], mx);
      resc[i] = expf(m_run[i] - nm);
      m_run[i] = nm;
      float sum = 0.f;
      #pragma unroll
      for (int ct = 0; ct < 4; ++ct) {
        const float e = expf(pv[ct][i] - nm);
        pv[ct][i] = e;
        sum += e;
      }
      #pragma unroll
      for (int d = 1; d < 16; d <<= 1) sum += __shfl_xor(sum, d);
      l_run[i] = l_run[i] * resc[i] + sum;
    }

    // P -> LDS (bf16), per-wave region; same-wave RAW ordered by lgkmcnt
    unsigned short* Pw = &Ps[w * 16 * LDP];
    #pragma unroll
    for (int ct = 0; ct < 4; ++ct)
      #pragma unroll
      for (int i = 0; i < 4; ++i)
        Pw[(fg * 4 + i) * LDP + ct * 16 + fr] = f2bf(pv[ct][i]);

    // rescale O^T (per-lane q = lane&15)
    const float rq = bcast_row16(resc[0], resc[1], resc[2], resc[3], lane);
    #pragma unroll
    for (int oc = 0; oc < 8; ++oc)
      #pragma unroll
      for (int e = 0; e < 4; ++e) ot[oc][e] *= rq;

    // PV (swapped): O^T[d][q] += V^T[d][kv] * P^T[kv][q]
    // A-fragment (V^T): row m = d = oc*16+fr, k = kv = kk2*32 + fg*8 + e
    // — now a single swizzled ds_read_b128 per (kk2, oc)
    #pragma unroll
    for (int kk2 = 0; kk2 < 2; ++kk2) {
      const short8 pf = *(const short8*)&Pw[fr * LDP + kk2 * 32 + fg * 8];
      #pragma unroll
      for (int oc = 0; oc < 8; ++oc) {
        const short8 vf = *(const short8*)&Vt[vt_off(oc * 16 + fr, kk2 * 32 + fg * 8)];
        ot[oc] = __builtin_amdgcn_mfma_f32_16x16x32_bf16(vf, pf, ot[oc], 0, 0, 0);
      }
    }
  }

  // epilogue: divide by l (per q), store O (lane holds 4 consecutive d per tile)
  const float invq = bcast_row16(1.f / l_run[0], 1.f / l_run[1],
                                 1.f / l_run[2], 1.f / l_run[3], lane);
  const size_t orow = (size_t)(b * SS + q0 + w * 16) + (lane & 15);
  #pragma unroll
  for (int oc = 0; oc < 8; ++oc) {
    const unsigned short e0 = f2bf(ot[oc][0] * invq);
    const unsigned short e1 = f2bf(ot[oc][1] * invq);
    const unsigned short e2 = f2bf(ot[oc][2] * invq);
    const unsigned short e3 = f2bf(ot[oc][3] * invq);
    const uint2 val = make_uint2((unsigned)e0 | ((unsigned)e1 << 16),
                                 (unsigned)e2 | ((unsigned)e3 << 16));
    *(uint2*)&out[orow * MODEL_DIM + h * HEAD_DIM + oc * 16 + fg * 4] = val;
  }
}

// ---------------------------------------------------------------- launch
extern "C" void kernel_launch(void* const* d_in, const int* in_sizes, int n_in,
                              void* d_out, int out_size, void* d_ws, size_t ws_size,
                              hipStream_t stream) {
  const float* x  = (const float*)d_in[0];
  const float* wq = (const float*)d_in[1];
  const float* wk = (const float*)d_in[2];
  const float* wv = (const float*)d_in[3];
  const float* wo = (const float*)d_in[4];
  const int* pos  = (const int*)d_in[6];        // mask (d_in[5]) unused: causal computed in-kernel
  float* out = (float*)d_out;

  // workspace layout (bf16 elements), total ≈ 202 MB
  unsigned short* xb   = (unsigned short*)d_ws;
  unsigned short* wqkv = xb   + (size_t)ROWS * MODEL_DIM;
  unsigned short* wob  = wqkv + (size_t)QKVN * MODEL_DIM;
  unsigned short* qkv  = wob  + (size_t)MODEL_DIM * MODEL_DIM;
  unsigned short* attn = qkv  + (size_t)ROWS * QKVN;

  cvt_bf16<<<2048, 256, 0, stream>>>(x,  xb,   ROWS * MODEL_DIM / 4);
  cvt_bf16<<<2048, 256, 0, stream>>>(wq, wqkv, MODEL_DIM * MODEL_DIM / 4);
  cvt_bf16<<<1024, 256, 0, stream>>>(wk, wqkv + (size_t)MODEL_DIM * MODEL_DIM,          NKV * HEAD_DIM * MODEL_DIM / 4);
  cvt_bf16<<<1024, 256, 0, stream>>>(wv, wqkv + (size_t)(MODEL_DIM + NKV * HEAD_DIM) * MODEL_DIM, NKV * HEAD_DIM * MODEL_DIM / 4);
  cvt_bf16<<<2048, 256, 0, stream>>>(wo, wob,  MODEL_DIM * MODEL_DIM / 4);

  gemm_bt<0><<<dim3((ROWS / 128) * (QKVN / 128)), 256, 0, stream>>>(xb, wqkv, qkv, ROWS, QKVN, MODEL_DIM);
  rope_kernel<<<ROWS, 256, 0, stream>>>(qkv, pos);
  attn_kernel<<<dim3(SS / QBLK, BB * NH), 256, 0, stream>>>(qkv, attn);
  gemm_bt<1><<<dim3((ROWS / 128) * (MODEL_DIM / 128)), 256, 0, stream>>>(attn, wob, out, ROWS, MODEL_DIM, MODEL_DIM);
}

// Round 4
// 1106.237 us; speedup vs baseline: 1.1160x; 1.0461x over previous
//
#include <hip/hip_runtime.h>
#include <hip/hip_bf16.h>
#include <stdint.h>

#define MODEL_DIM 4096
#define HEAD_DIM  128
#define NH        32
#define NKV       8
#define BB        2
#define SS        2048
#define ROWS      (BB*SS)                        // 4096
#define QKVN      (MODEL_DIM + 2*NKV*HEAD_DIM)   // 6144
#define KOFF      MODEL_DIM                      // 4096
#define VOFF      (MODEL_DIM + NKV*HEAD_DIM)     // 5120
#define SCALE_QK  0.08838834764831845f           // 1/sqrt(128)

typedef __attribute__((ext_vector_type(8))) short short8;
typedef __attribute__((ext_vector_type(4))) float f32x4;

static __device__ __forceinline__ unsigned short f2bf(float f) {
  union { float f; unsigned u; } v; v.f = f;
  unsigned r = v.u + 0x7fffu + ((v.u >> 16) & 1u);   // round-to-nearest-even
  return (unsigned short)(r >> 16);
}
static __device__ __forceinline__ float bf2f(unsigned short u) {
  union { unsigned u; float f; } v; v.u = ((unsigned)u) << 16;
  return v.f;
}
static __device__ __forceinline__ void glds16(const unsigned short* g, const unsigned short* l) {
  __builtin_amdgcn_global_load_lds((const __attribute__((address_space(1))) void*)g,
      (__attribute__((address_space(3))) void*)l, 16, 0, 0);
}

// ---------------------------------------------------------------- converts
__global__ void cvt_bf16(const float* __restrict__ s, unsigned short* __restrict__ d, int n4) {
  int i = blockIdx.x * blockDim.x + threadIdx.x;
  int st = gridDim.x * blockDim.x;
  for (; i < n4; i += st) {
    float4 v = reinterpret_cast<const float4*>(s)[i];
    ushort4 o;
    o.x = f2bf(v.x); o.y = f2bf(v.y); o.z = f2bf(v.z); o.w = f2bf(v.w);
    reinterpret_cast<ushort4*>(d)[i] = o;
  }
}

// ---------------------------------------------------------------- GEMM  C = A * B^T  (m97 structure)
template<int OUT_F32>
__global__ __launch_bounds__(256) void gemm_bt(
    const unsigned short* __restrict__ A, const unsigned short* __restrict__ B,
    void* __restrict__ Cv, int M, int N, int K)
{
  __shared__ unsigned short As[128 * 32];
  __shared__ unsigned short Bs[128 * 32];
  const int tid  = threadIdx.x;
  const int lane = tid & 63;
  const int w    = tid >> 6;

  const int nwg = gridDim.x;
  const int bid = blockIdx.x;
  const int q8  = nwg >> 3;
  const int wg  = (bid & 7) * q8 + (bid >> 3);
  const int gm  = M >> 7;
  const int bm  = wg % gm, bn = wg / gm;
  const int m0  = bm << 7, n0 = bn << 7;
  const int wm  = (w >> 1) << 6, wn = (w & 1) << 6;

  f32x4 acc[4][4] = {};

  const int rowA = lane >> 2;
  const int ch8  = (lane & 3) * 8;

  for (int k0 = 0; k0 < K; k0 += 32) {
    __syncthreads();
    #pragma unroll
    for (int i = 0; i < 2; ++i) {
      const unsigned short* ga = A + (size_t)(m0 + i*64 + w*16 + rowA) * K + k0 + ch8;
      glds16(ga, &As[(i*64 + w*16) * 32]);
      const unsigned short* gb = B + (size_t)(n0 + i*64 + w*16 + rowA) * K + k0 + ch8;
      glds16(gb, &Bs[(i*64 + w*16) * 32]);
    }
    __syncthreads();

    short8 af[4], bf[4];
    const int fr = lane & 15, fg = lane >> 4;
    #pragma unroll
    for (int r = 0; r < 4; ++r)
      af[r] = *(const short8*)&As[(wm + r*16 + fr) * 32 + fg * 8];
    #pragma unroll
    for (int r = 0; r < 4; ++r)
      bf[r] = *(const short8*)&Bs[(wn + r*16 + fr) * 32 + fg * 8];
    #pragma unroll
    for (int i = 0; i < 4; ++i)
      #pragma unroll
      for (int j = 0; j < 4; ++j)
        acc[i][j] = __builtin_amdgcn_mfma_f32_16x16x32_bf16(af[i], bf[j], acc[i][j], 0, 0, 0);
  }

  const int cr = (lane >> 4) * 4, cc = lane & 15;
  #pragma unroll
  for (int i = 0; i < 4; ++i)
    #pragma unroll
    for (int j = 0; j < 4; ++j) {
      const int gr = m0 + wm + i*16 + cr;
      const int gc = n0 + wn + j*16 + cc;
      #pragma unroll
      for (int e = 0; e < 4; ++e) {
        const float v = acc[i][j][e];
        if (OUT_F32) ((float*)Cv)[(size_t)(gr + e) * N + gc] = v;
        else ((unsigned short*)Cv)[(size_t)(gr + e) * N + gc] = f2bf(v);
      }
    }
}

// ---------------------------------------------------------------- RoPE (in-place, Q + K)
__global__ void rope_kernel(unsigned short* __restrict__ qkv, const int* __restrict__ posp) {
  const int row = blockIdx.x;
  const float t = (float)((row & (SS - 1)) + posp[0]);
  const float c0 = -13.28771237954945f / 64.0f;     // -log2(10000)/64
  for (int i = threadIdx.x; i < (NH + NKV) * 64; i += blockDim.x) {
    const int hh = i >> 6, p = i & 63;
    const int colbase = (hh < NH) ? hh * HEAD_DIM : KOFF + (hh - NH) * HEAD_DIM;
    const float inv = exp2f((float)p * c0);
    float sn, cs;
    sincosf(t * inv, &sn, &cs);
    const size_t base = (size_t)row * QKVN + colbase + 2 * p;
    const float x1 = bf2f(qkv[base]), x2 = bf2f(qkv[base + 1]);
    qkv[base]     = f2bf(x1 * cs - x2 * sn);
    qkv[base + 1] = f2bf(x1 * sn + x2 * cs);
  }
}

// ---------------------------------------------------------------- V transpose: vt[bk][d=128][s=2048]
// LDS tile [64 s][128 d], 16B-slot XOR swizzle by (s>>3)&7 on low-3 slot bits.
__global__ __launch_bounds__(256) void vtrans_kernel(
    const unsigned short* __restrict__ qkv, unsigned short* __restrict__ vt)
{
  __shared__ unsigned short T[64 * 128];
  const int tid = threadIdx.x;
  const int bk  = blockIdx.y;                  // b*NKV + kvh
  const int s0  = blockIdx.x * 64;
  const int b   = bk >> 3, kvh = bk & 7;

  #pragma unroll
  for (int it = 0; it < 4; ++it) {
    const int cid  = it * 256 + tid;
    const int s    = cid >> 4, slot = cid & 15;
    const int sl   = (slot & 8) | ((slot ^ (s >> 3)) & 7);
    *(uint4*)&T[s * 128 + sl * 8] =
      *(const uint4*)&qkv[(size_t)(b * SS + s0 + s) * QKVN + VOFF + kvh * HEAD_DIM + slot * 8];
  }
  __syncthreads();
  #pragma unroll
  for (int it = 0; it < 4; ++it) {
    const int cid = it * 256 + tid;
    const int d   = cid >> 3, s8 = (cid & 7) * 8;
    unsigned short tmp[8];
    #pragma unroll
    for (int j = 0; j < 8; ++j) {
      const int s    = s8 + j;
      const int slot = d >> 3;
      const int sl   = (slot & 8) | ((slot ^ (s >> 3)) & 7);
      tmp[j] = T[s * 128 + sl * 8 + (d & 7)];
    }
    *(uint4*)&vt[((size_t)bk * HEAD_DIM + d) * SS + s0 + s8] = *(uint4*)tmp;
  }
}

// ---------------------------------------------------------------- flash attention (causal, GQA 4:1)
#define QBLK 64
#define KVB  64
#define LDP  72

static __device__ __forceinline__ float bcast_row16(float v0, float v1, float v2, float v3, int lane) {
  const int sel = (lane >> 2) & 3;
  const float a = (sel & 1) ? v1 : v0;
  const float b = (sel & 1) ? v3 : v2;
  const float m = (sel & 2) ? b : a;
  const int q = lane & 15;
  return __shfl(m, ((q >> 2) << 4) + ((q & 3) << 2));
}

__global__ __launch_bounds__(256) void attn_kernel(
    const unsigned short* __restrict__ qkv, const unsigned short* __restrict__ vt,
    unsigned short* __restrict__ out)
{
  // double-buffered K (row-major [64][128]) and V^T ([128][64]), both 16B-slot
  // XOR-swizzled (slot ^= row&7 / d&7) via pre-swizzled global_load_lds source.
  __shared__ unsigned short Kb[2][KVB * HEAD_DIM];      // 2 x 16 KiB
  __shared__ unsigned short Vb[2][HEAD_DIM * KVB];      // 2 x 16 KiB
  __shared__ unsigned short Ps[4 * 16 * LDP];           // 9216 B

  const int tid  = threadIdx.x;
  const int lane = tid & 63;
  const int w    = tid >> 6;
  const int bh   = blockIdx.y;            // b*32 + h
  const int b    = bh >> 5, h = bh & 31;
  const int kvh  = h >> 2;
  const int q0   = (gridDim.x - 1 - blockIdx.x) * QBLK;   // heavy blocks first
  const int fr   = lane & 15, fg = lane >> 4;

  const unsigned short* kg  = qkv + KOFF + kvh * HEAD_DIM;
  const unsigned short* vtg = vt + (size_t)(b * NKV + kvh) * HEAD_DIM * SS;

  // Q fragments (A-operand: row=lane&15, k=(lane>>4)*8+i)
  const size_t qrow0 = (size_t)(b * SS + q0 + w * 16);
  short8 qf[4];
  #pragma unroll
  for (int kk = 0; kk < 4; ++kk)
    qf[kk] = *(const short8*)&qkv[(qrow0 + fr) * QKVN + h * HEAD_DIM + kk * 32 + fg * 8];

  f32x4 ot[8] = {};
  float m_run[4], l_run[4];
  #pragma unroll
  for (int i = 0; i < 4; ++i) { m_run[i] = -INFINITY; l_run[i] = 0.f; }

  // staging lane constants
  const int krow_l = lane >> 4;                 // K: 4 rows/instr
  const int kslot  = lane & 15;
  const int vrow_l = lane >> 3;                 // Vt: 8 d-rows/instr
  const int vslot  = lane & 7;

  const int ntile = (q0 >> 6) + 1;

  // ---- prologue: stage tile 0 into buffer 0
  {
    const int j0 = 0;
    #pragma unroll
    for (int i = 0; i < 4; ++i) {
      const int r  = w * 16 + i * 4 + krow_l;
      const int gs = (kslot & 8) | ((kslot ^ r) & 7);
      glds16(kg + (size_t)(b * SS + j0 + r) * QKVN + gs * 8, &Kb[0][(w * 16 + i * 4) * 128]);
      const int d  = w * 32 + i * 8 + vrow_l;
      const int vg = vslot ^ (d & 7);
      glds16(vtg + (size_t)d * SS + j0 + vg * 8, &Vb[0][(w * 32 + i * 8) * 64]);
    }
  }

  int cur = 0;
  for (int jt = 0; jt < ntile; ++jt) {
    __syncthreads();                       // stage(jt) landed; buf[cur^1] free
    if (jt + 1 < ntile) {                  // async prefetch next tile
      const int j0n = (jt + 1) * KVB;
      #pragma unroll
      for (int i = 0; i < 4; ++i) {
        const int r  = w * 16 + i * 4 + krow_l;
        const int gs = (kslot & 8) | ((kslot ^ r) & 7);
        glds16(kg + (size_t)(b * SS + j0n + r) * QKVN + gs * 8, &Kb[cur ^ 1][(w * 16 + i * 4) * 128]);
        const int d  = w * 32 + i * 8 + vrow_l;
        const int vg = vslot ^ (d & 7);
        glds16(vtg + (size_t)d * SS + j0n + vg * 8, &Vb[cur ^ 1][(w * 32 + i * 8) * 64]);
      }
    }
    const unsigned short* Kc = Kb[cur];
    const unsigned short* Vc = Vb[cur];
    const bool diag = (jt == ntile - 1);

    // QK^T: swizzled ds_read_b128 of K fragments
    float pv[4][4];
    #pragma unroll
    for (int ct = 0; ct < 4; ++ct) {
      f32x4 s = {};
      const int krow = ct * 16 + fr;
      #pragma unroll
      for (int kk = 0; kk < 4; ++kk) {
        const int c  = kk * 4 + fg;
        const int sl = (c & 8) | ((c ^ krow) & 7);
        const short8 kf = *(const short8*)&Kc[krow * 128 + sl * 8];
        s = __builtin_amdgcn_mfma_f32_16x16x32_bf16(qf[kk], kf, s, 0, 0, 0);
      }
      #pragma unroll
      for (int i = 0; i < 4; ++i) {
        float v = s[i] * SCALE_QK;
        if (diag) {
          const int qr = w * 16 + fg * 4 + i;
          const int kc = ct * 16 + fr;
          if (kc > qr) v = -INFINITY;
        }
        pv[ct][i] = v;
      }
    }

    // online softmax
    float resc[4];
    #pragma unroll
    for (int i = 0; i < 4; ++i) {
      float mx = fmaxf(fmaxf(pv[0][i], pv[1][i]), fmaxf(pv[2][i], pv[3][i]));
      #pragma unroll
      for (int d = 1; d < 16; d <<= 1) mx = fmaxf(mx, __shfl_xor(mx, d));
      const float nm = fmaxf(m_run[i], mx);
      resc[i] = expf(m_run[i] - nm);
      m_run[i] = nm;
      float sum = 0.f;
      #pragma unroll
      for (int ct = 0; ct < 4; ++ct) {
        const float e = expf(pv[ct][i] - nm);
        pv[ct][i] = e;
        sum += e;
      }
      #pragma unroll
      for (int d = 1; d < 16; d <<= 1) sum += __shfl_xor(sum, d);
      l_run[i] = l_run[i] * resc[i] + sum;
    }

    // P -> LDS (wave-private region)
    unsigned short* Pw = &Ps[w * 16 * LDP];
    #pragma unroll
    for (int ct = 0; ct < 4; ++ct)
      #pragma unroll
      for (int i = 0; i < 4; ++i)
        Pw[(fg * 4 + i) * LDP + ct * 16 + fr] = f2bf(pv[ct][i]);

    // rescale O^T
    const float rq = bcast_row16(resc[0], resc[1], resc[2], resc[3], lane);
    #pragma unroll
    for (int oc = 0; oc < 8; ++oc)
      #pragma unroll
      for (int e = 0; e < 4; ++e) ot[oc][e] *= rq;

    // PV (swapped): O^T[d][q] += V^T[d][kv] * P^T[kv][q]; swizzled b128 V reads
    #pragma unroll
    for (int kk2 = 0; kk2 < 2; ++kk2) {
      const short8 pf = *(const short8*)&Pw[fr * LDP + kk2 * 32 + fg * 8];
      #pragma unroll
      for (int oc = 0; oc < 8; ++oc) {
        const int vd = oc * 16 + fr;
        const int sl = (kk2 * 4 + fg) ^ (vd & 7);
        const short8 vf = *(const short8*)&Vc[vd * 64 + sl * 8];
        ot[oc] = __builtin_amdgcn_mfma_f32_16x16x32_bf16(vf, pf, ot[oc], 0, 0, 0);
      }
    }
    cur ^= 1;
  }

  // epilogue
  const float invq = bcast_row16(1.f / l_run[0], 1.f / l_run[1],
                                 1.f / l_run[2], 1.f / l_run[3], lane);
  const size_t orow = (size_t)(b * SS + q0 + w * 16) + (lane & 15);
  #pragma unroll
  for (int oc = 0; oc < 8; ++oc) {
    const unsigned short e0 = f2bf(ot[oc][0] * invq);
    const unsigned short e1 = f2bf(ot[oc][1] * invq);
    const unsigned short e2 = f2bf(ot[oc][2] * invq);
    const unsigned short e3 = f2bf(ot[oc][3] * invq);
    const uint2 val = make_uint2((unsigned)e0 | ((unsigned)e1 << 16),
                                 (unsigned)e2 | ((unsigned)e3 << 16));
    *(uint2*)&out[orow * MODEL_DIM + h * HEAD_DIM + oc * 16 + fg * 4] = val;
  }
}

// ---------------------------------------------------------------- launch
extern "C" void kernel_launch(void* const* d_in, const int* in_sizes, int n_in,
                              void* d_out, int out_size, void* d_ws, size_t ws_size,
                              hipStream_t stream) {
  const float* x  = (const float*)d_in[0];
  const float* wq = (const float*)d_in[1];
  const float* wk = (const float*)d_in[2];
  const float* wv = (const float*)d_in[3];
  const float* wo = (const float*)d_in[4];
  const int* pos  = (const int*)d_in[6];        // mask (d_in[5]) unused: causal in-kernel
  float* out = (float*)d_out;

  // workspace layout (bf16 elements), ~202 MB total
  unsigned short* xb   = (unsigned short*)d_ws;
  unsigned short* wqkv = xb   + (size_t)ROWS * MODEL_DIM;
  unsigned short* wob  = wqkv + (size_t)QKVN * MODEL_DIM;
  unsigned short* qkv  = wob  + (size_t)MODEL_DIM * MODEL_DIM;
  unsigned short* attn = qkv  + (size_t)ROWS * QKVN;
  unsigned short* vtb  = xb;   // reuse: xb is dead after gemm1 (8 MB needed of 33.5 MB)

  cvt_bf16<<<2048, 256, 0, stream>>>(x,  xb,   ROWS * MODEL_DIM / 4);
  cvt_bf16<<<2048, 256, 0, stream>>>(wq, wqkv, MODEL_DIM * MODEL_DIM / 4);
  cvt_bf16<<<1024, 256, 0, stream>>>(wk, wqkv + (size_t)MODEL_DIM * MODEL_DIM,          NKV * HEAD_DIM * MODEL_DIM / 4);
  cvt_bf16<<<1024, 256, 0, stream>>>(wv, wqkv + (size_t)(MODEL_DIM + NKV * HEAD_DIM) * MODEL_DIM, NKV * HEAD_DIM * MODEL_DIM / 4);
  cvt_bf16<<<2048, 256, 0, stream>>>(wo, wob,  MODEL_DIM * MODEL_DIM / 4);

  gemm_bt<0><<<dim3((ROWS / 128) * (QKVN / 128)), 256, 0, stream>>>(xb, wqkv, qkv, ROWS, QKVN, MODEL_DIM);
  rope_kernel<<<ROWS, 256, 0, stream>>>(qkv, pos);
  vtrans_kernel<<<dim3(SS / 64, BB * NKV), 256, 0, stream>>>(qkv, vtb);
  attn_kernel<<<dim3(SS / QBLK, BB * NH), 256, 0, stream>>>(qkv, vtb, attn);
  gemm_bt<1><<<dim3((ROWS / 128) * (MODEL_DIM / 128)), 256, 0, stream>>>(attn, wob, out, ROWS, MODEL_DIM, MODEL_DIM);
}

// Round 5
// 976.674 us; speedup vs baseline: 1.2640x; 1.1327x over previous
//
#include <hip/hip_runtime.h>
#include <hip/hip_bf16.h>
#include <stdint.h>

#define MODEL_DIM 4096
#define HEAD_DIM  128
#define NH        32
#define NKV       8
#define BB        2
#define SS        2048
#define ROWS      (BB*SS)                        // 4096
#define QKVN      (MODEL_DIM + 2*NKV*HEAD_DIM)   // 6144
#define KOFF      MODEL_DIM                      // 4096
#define VOFF      (MODEL_DIM + NKV*HEAD_DIM)     // 5120
#define SCALE_QK  0.08838834764831845f           // 1/sqrt(128)
#define SCALE_E2  0.12753102198681652f           // SCALE_QK * log2(e): exp2 domain

typedef __attribute__((ext_vector_type(8))) short short8;
typedef __attribute__((ext_vector_type(4))) float f32x4;

static __device__ __forceinline__ unsigned short f2bf(float f) {
  union { float f; unsigned u; } v; v.f = f;
  unsigned r = v.u + 0x7fffu + ((v.u >> 16) & 1u);   // round-to-nearest-even
  return (unsigned short)(r >> 16);
}
static __device__ __forceinline__ float bf2f(unsigned short u) {
  union { unsigned u; float f; } v; v.u = ((unsigned)u) << 16;
  return v.f;
}
static __device__ __forceinline__ void glds16(const unsigned short* g, const unsigned short* l) {
  __builtin_amdgcn_global_load_lds((const __attribute__((address_space(1))) void*)g,
      (__attribute__((address_space(3))) void*)l, 16, 0, 0);
}

// ---------------------------------------------------------------- converts
__global__ void cvt_bf16(const float* __restrict__ s, unsigned short* __restrict__ d, int n4) {
  int i = blockIdx.x * blockDim.x + threadIdx.x;
  int st = gridDim.x * blockDim.x;
  for (; i < n4; i += st) {
    float4 v = reinterpret_cast<const float4*>(s)[i];
    ushort4 o;
    o.x = f2bf(v.x); o.y = f2bf(v.y); o.z = f2bf(v.z); o.w = f2bf(v.w);
    reinterpret_cast<ushort4*>(d)[i] = o;
  }
}

// ---------------------------------------------------------------- GEMM  C = A * B^T  (m97 structure)
template<int OUT_F32>
__global__ __launch_bounds__(256) void gemm_bt(
    const unsigned short* __restrict__ A, const unsigned short* __restrict__ B,
    void* __restrict__ Cv, int M, int N, int K)
{
  __shared__ unsigned short As[128 * 32];
  __shared__ unsigned short Bs[128 * 32];
  const int tid  = threadIdx.x;
  const int lane = tid & 63;
  const int w    = tid >> 6;

  const int nwg = gridDim.x;
  const int bid = blockIdx.x;
  const int q8  = nwg >> 3;
  const int wg  = (bid & 7) * q8 + (bid >> 3);
  const int gm  = M >> 7;
  const int bm  = wg % gm, bn = wg / gm;
  const int m0  = bm << 7, n0 = bn << 7;
  const int wm  = (w >> 1) << 6, wn = (w & 1) << 6;

  f32x4 acc[4][4] = {};

  const int rowA = lane >> 2;
  const int ch8  = (lane & 3) * 8;

  for (int k0 = 0; k0 < K; k0 += 32) {
    __syncthreads();
    #pragma unroll
    for (int i = 0; i < 2; ++i) {
      const unsigned short* ga = A + (size_t)(m0 + i*64 + w*16 + rowA) * K + k0 + ch8;
      glds16(ga, &As[(i*64 + w*16) * 32]);
      const unsigned short* gb = B + (size_t)(n0 + i*64 + w*16 + rowA) * K + k0 + ch8;
      glds16(gb, &Bs[(i*64 + w*16) * 32]);
    }
    __syncthreads();

    short8 af[4], bf[4];
    const int fr = lane & 15, fg = lane >> 4;
    #pragma unroll
    for (int r = 0; r < 4; ++r)
      af[r] = *(const short8*)&As[(wm + r*16 + fr) * 32 + fg * 8];
    #pragma unroll
    for (int r = 0; r < 4; ++r)
      bf[r] = *(const short8*)&Bs[(wn + r*16 + fr) * 32 + fg * 8];
    #pragma unroll
    for (int i = 0; i < 4; ++i)
      #pragma unroll
      for (int j = 0; j < 4; ++j)
        acc[i][j] = __builtin_amdgcn_mfma_f32_16x16x32_bf16(af[i], bf[j], acc[i][j], 0, 0, 0);
  }

  const int cr = (lane >> 4) * 4, cc = lane & 15;
  #pragma unroll
  for (int i = 0; i < 4; ++i)
    #pragma unroll
    for (int j = 0; j < 4; ++j) {
      const int gr = m0 + wm + i*16 + cr;
      const int gc = n0 + wn + j*16 + cc;
      #pragma unroll
      for (int e = 0; e < 4; ++e) {
        const float v = acc[i][j][e];
        if (OUT_F32) ((float*)Cv)[(size_t)(gr + e) * N + gc] = v;
        else ((unsigned short*)Cv)[(size_t)(gr + e) * N + gc] = f2bf(v);
      }
    }
}

// ---------------------------------------------------------------- RoPE (in-place, Q + K)
__global__ void rope_kernel(unsigned short* __restrict__ qkv, const int* __restrict__ posp) {
  const int row = blockIdx.x;
  const float t = (float)((row & (SS - 1)) + posp[0]);
  const float c0 = -13.28771237954945f / 64.0f;     // -log2(10000)/64
  for (int i = threadIdx.x; i < (NH + NKV) * 64; i += blockDim.x) {
    const int hh = i >> 6, p = i & 63;
    const int colbase = (hh < NH) ? hh * HEAD_DIM : KOFF + (hh - NH) * HEAD_DIM;
    const float inv = exp2f((float)p * c0);
    float sn, cs;
    sincosf(t * inv, &sn, &cs);
    const size_t base = (size_t)row * QKVN + colbase + 2 * p;
    const float x1 = bf2f(qkv[base]), x2 = bf2f(qkv[base + 1]);
    qkv[base]     = f2bf(x1 * cs - x2 * sn);
    qkv[base + 1] = f2bf(x1 * sn + x2 * cs);
  }
}

// ---------------------------------------------------------------- V transpose: vt[bk][d=128][s=2048]
// Columns within each 64-block are stored in PV-slot order: position kv' holds
// actual kv = sigma(kv') = (kv'&0x23) | ((kv'&4)<<2) | ((kv'&0x18)>>1),
// matching the register layout of the swapped-QK P fragments (see attn_kernel).
// LDS tile [64 s][128 d], 16B-slot XOR swizzle by (s>>3)&7 on low-3 slot bits.
__global__ __launch_bounds__(256) void vtrans_kernel(
    const unsigned short* __restrict__ qkv, unsigned short* __restrict__ vt)
{
  __shared__ unsigned short T[64 * 128];
  const int tid = threadIdx.x;
  const int bk  = blockIdx.y;                  // b*NKV + kvh
  const int s0  = blockIdx.x * 64;
  const int b   = bk >> 3, kvh = bk & 7;

  #pragma unroll
  for (int it = 0; it < 4; ++it) {
    const int cid  = it * 256 + tid;
    const int s    = cid >> 4, slot = cid & 15;
    const int sl   = (slot & 8) | ((slot ^ (s >> 3)) & 7);
    *(uint4*)&T[s * 128 + sl * 8] =
      *(const uint4*)&qkv[(size_t)(b * SS + s0 + s) * QKVN + VOFF + kvh * HEAD_DIM + slot * 8];
  }
  __syncthreads();
  #pragma unroll
  for (int it = 0; it < 4; ++it) {
    const int cid = it * 256 + tid;
    const int d   = cid >> 3, s8 = (cid & 7) * 8;
    unsigned short tmp[8];
    #pragma unroll
    for (int j = 0; j < 8; ++j) {
      const int so   = s8 + j;                                     // PV-slot position
      const int si   = (so & 0x23) | ((so & 4) << 2) | ((so & 0x18) >> 1);  // actual kv
      const int slot = d >> 3;
      const int sl   = (slot & 8) | ((slot ^ (si >> 3)) & 7);
      tmp[j] = T[si * 128 + sl * 8 + (d & 7)];
    }
    *(uint4*)&vt[((size_t)bk * HEAD_DIM + d) * SS + s0 + s8] = *(uint4*)tmp;
  }
}

// ---------------------------------------------------------------- flash attention (causal, GQA 4:1)
// Swapped QK^T: s = mfma(K, Q) -> lane holds 16 scores for ONE q (q = lane&15,
// kv = 16ct + 4fg + e). Softmax fully in-register (2 shfl_xor per reduce);
// P feeds PV's B-operand directly (kv-slot order handled by vtrans's sigma).
#define QBLK 64
#define KVB  64

__global__ __launch_bounds__(256) void attn_kernel(
    const unsigned short* __restrict__ qkv, const unsigned short* __restrict__ vt,
    unsigned short* __restrict__ out)
{
  __shared__ unsigned short Kb[2][KVB * HEAD_DIM];      // 2 x 16 KiB
  __shared__ unsigned short Vb[2][HEAD_DIM * KVB];      // 2 x 16 KiB

  const int tid  = threadIdx.x;
  const int lane = tid & 63;
  const int w    = tid >> 6;
  const int bh   = blockIdx.y;            // b*32 + h
  const int b    = bh >> 5, h = bh & 31;
  const int kvh  = h >> 2;
  const int q0   = (gridDim.x - 1 - blockIdx.x) * QBLK;   // heavy blocks first
  const int fr   = lane & 15, fg = lane >> 4;

  const unsigned short* kg  = qkv + KOFF + kvh * HEAD_DIM;
  const unsigned short* vtg = vt + (size_t)(b * NKV + kvh) * HEAD_DIM * SS;

  // Q fragments (B-operand: col=lane&15=q, k=(lane>>4)*8+j)
  const size_t qrow0 = (size_t)(b * SS + q0 + w * 16);
  short8 qf[4];
  #pragma unroll
  for (int kk = 0; kk < 4; ++kk)
    qf[kk] = *(const short8*)&qkv[(qrow0 + fr) * QKVN + h * HEAD_DIM + kk * 32 + fg * 8];

  f32x4 ot[8] = {};                        // O^T tiles: col=q=lane&15, row d=oc*16+4fg+e
  float m_run = -INFINITY, l_run = 0.f;    // per-lane (per-q) online softmax state

  // staging lane constants
  const int krow_l = lane >> 4;                 // K: 4 rows/instr
  const int kslot  = lane & 15;
  const int vrow_l = lane >> 3;                 // Vt: 8 d-rows/instr
  const int vslot  = lane & 7;

  const int ntile = (q0 >> 6) + 1;

  // ---- prologue: stage tile 0 into buffer 0
  {
    #pragma unroll
    for (int i = 0; i < 4; ++i) {
      const int r  = w * 16 + i * 4 + krow_l;
      const int gs = (kslot & 8) | ((kslot ^ r) & 7);
      glds16(kg + (size_t)(b * SS + r) * QKVN + gs * 8, &Kb[0][(w * 16 + i * 4) * 128]);
      const int d  = w * 32 + i * 8 + vrow_l;
      const int vg = vslot ^ (d & 7);
      glds16(vtg + (size_t)d * SS + vg * 8, &Vb[0][(w * 32 + i * 8) * 64]);
    }
  }

  int cur = 0;
  for (int jt = 0; jt < ntile; ++jt) {
    __syncthreads();                       // stage(jt) landed; buf[cur^1] free
    if (jt + 1 < ntile) {                  // async prefetch next tile
      const int j0n = (jt + 1) * KVB;
      #pragma unroll
      for (int i = 0; i < 4; ++i) {
        const int r  = w * 16 + i * 4 + krow_l;
        const int gs = (kslot & 8) | ((kslot ^ r) & 7);
        glds16(kg + (size_t)(b * SS + j0n + r) * QKVN + gs * 8, &Kb[cur ^ 1][(w * 16 + i * 4) * 128]);
        const int d  = w * 32 + i * 8 + vrow_l;
        const int vg = vslot ^ (d & 7);
        glds16(vtg + (size_t)d * SS + j0n + vg * 8, &Vb[cur ^ 1][(w * 32 + i * 8) * 64]);
      }
    }
    const unsigned short* Kc = Kb[cur];
    const unsigned short* Vc = Vb[cur];
    const bool diag = (jt == ntile - 1);

    // QK^T (swapped): p[ct][e] = S^T, q = fr, kv = ct*16 + 4*fg + e; exp2 domain
    float p[4][4];
    #pragma unroll
    for (int ct = 0; ct < 4; ++ct) {
      f32x4 s = {};
      const int krow = ct * 16 + fr;
      #pragma unroll
      for (int kk = 0; kk < 4; ++kk) {
        const int c  = kk * 4 + fg;
        const int sl = (c & 8) | ((c ^ krow) & 7);
        const short8 kf = *(const short8*)&Kc[krow * 128 + sl * 8];
        s = __builtin_amdgcn_mfma_f32_16x16x32_bf16(kf, qf[kk], s, 0, 0, 0);
      }
      #pragma unroll
      for (int e = 0; e < 4; ++e) {
        float v = s[e] * SCALE_E2;
        if (diag) {
          const int kc = ct * 16 + fg * 4 + e;   // kv within tile
          const int qr = w * 16 + fr;            // q within block (j0 == q0)
          if (kc > qr) v = -INFINITY;
        }
        p[ct][e] = v;
      }
    }

    // online softmax, fully per-lane (one q per lane; fg quartet shares q)
    float mx = p[0][0];
    #pragma unroll
    for (int ct = 0; ct < 4; ++ct)
      #pragma unroll
      for (int e = 0; e < 4; ++e) mx = fmaxf(mx, p[ct][e]);
    mx = fmaxf(mx, __shfl_xor(mx, 16));
    mx = fmaxf(mx, __shfl_xor(mx, 32));
    const float nm   = fmaxf(m_run, mx);
    const float resc = exp2f(m_run - nm);
    m_run = nm;
    float sum = 0.f;
    #pragma unroll
    for (int ct = 0; ct < 4; ++ct)
      #pragma unroll
      for (int e = 0; e < 4; ++e) {
        const float pe = exp2f(p[ct][e] - nm);
        p[ct][e] = pe;
        sum += pe;
      }
    sum += __shfl_xor(sum, 16);
    sum += __shfl_xor(sum, 32);
    l_run = l_run * resc + sum;

    // pack P into PV B-fragments: slot (kk2, j) <- p[2*kk2 + (j>>2)][j&3]
    short8 pf0, pf1;
    #pragma unroll
    for (int e = 0; e < 4; ++e) {
      pf0[e]     = (short)f2bf(p[0][e]);
      pf0[e + 4] = (short)f2bf(p[1][e]);
      pf1[e]     = (short)f2bf(p[2][e]);
      pf1[e + 4] = (short)f2bf(p[3][e]);
    }

    // rescale O^T (per-lane)
    #pragma unroll
    for (int oc = 0; oc < 8; ++oc)
      #pragma unroll
      for (int e = 0; e < 4; ++e) ot[oc][e] *= resc;

    // PV (swapped): O^T[d][q] += V^T[d][kv] * P^T[kv][q]; swizzled b128 V reads.
    // Vt columns are pre-permuted (sigma) so linear slots match pf slot order.
    #pragma unroll
    for (int kk2 = 0; kk2 < 2; ++kk2) {
      const short8 pf = kk2 ? pf1 : pf0;
      #pragma unroll
      for (int oc = 0; oc < 8; ++oc) {
        const int vd = oc * 16 + fr;
        const int sl = (kk2 * 4 + fg) ^ (vd & 7);
        const short8 vf = *(const short8*)&Vc[vd * 64 + sl * 8];
        ot[oc] = __builtin_amdgcn_mfma_f32_16x16x32_bf16(vf, pf, ot[oc], 0, 0, 0);
      }
    }
    cur ^= 1;
  }

  // epilogue: divide by l (per-lane), store O
  const float invq = 1.f / l_run;
  const size_t orow = (size_t)(b * SS + q0 + w * 16) + (lane & 15);
  #pragma unroll
  for (int oc = 0; oc < 8; ++oc) {
    const unsigned short e0 = f2bf(ot[oc][0] * invq);
    const unsigned short e1 = f2bf(ot[oc][1] * invq);
    const unsigned short e2 = f2bf(ot[oc][2] * invq);
    const unsigned short e3 = f2bf(ot[oc][3] * invq);
    const uint2 val = make_uint2((unsigned)e0 | ((unsigned)e1 << 16),
                                 (unsigned)e2 | ((unsigned)e3 << 16));
    *(uint2*)&out[orow * MODEL_DIM + h * HEAD_DIM + oc * 16 + fg * 4] = val;
  }
}

// ---------------------------------------------------------------- launch
extern "C" void kernel_launch(void* const* d_in, const int* in_sizes, int n_in,
                              void* d_out, int out_size, void* d_ws, size_t ws_size,
                              hipStream_t stream) {
  const float* x  = (const float*)d_in[0];
  const float* wq = (const float*)d_in[1];
  const float* wk = (const float*)d_in[2];
  const float* wv = (const float*)d_in[3];
  const float* wo = (const float*)d_in[4];
  const int* pos  = (const int*)d_in[6];        // mask (d_in[5]) unused: causal in-kernel
  float* out = (float*)d_out;

  // workspace layout (bf16 elements), ~202 MB total
  unsigned short* xb   = (unsigned short*)d_ws;
  unsigned short* wqkv = xb   + (size_t)ROWS * MODEL_DIM;
  unsigned short* wob  = wqkv + (size_t)QKVN * MODEL_DIM;
  unsigned short* qkv  = wob  + (size_t)MODEL_DIM * MODEL_DIM;
  unsigned short* attn = qkv  + (size_t)ROWS * QKVN;
  unsigned short* vtb  = xb;   // reuse: xb is dead after gemm1 (8 MB needed of 33.5 MB)

  cvt_bf16<<<2048, 256, 0, stream>>>(x,  xb,   ROWS * MODEL_DIM / 4);
  cvt_bf16<<<2048, 256, 0, stream>>>(wq, wqkv, MODEL_DIM * MODEL_DIM / 4);
  cvt_bf16<<<1024, 256, 0, stream>>>(wk, wqkv + (size_t)MODEL_DIM * MODEL_DIM,          NKV * HEAD_DIM * MODEL_DIM / 4);
  cvt_bf16<<<1024, 256, 0, stream>>>(wv, wqkv + (size_t)(MODEL_DIM + NKV * HEAD_DIM) * MODEL_DIM, NKV * HEAD_DIM * MODEL_DIM / 4);
  cvt_bf16<<<2048, 256, 0, stream>>>(wo, wob,  MODEL_DIM * MODEL_DIM / 4);

  gemm_bt<0><<<dim3((ROWS / 128) * (QKVN / 128)), 256, 0, stream>>>(xb, wqkv, qkv, ROWS, QKVN, MODEL_DIM);
  rope_kernel<<<ROWS, 256, 0, stream>>>(qkv, pos);
  vtrans_kernel<<<dim3(SS / 64, BB * NKV), 256, 0, stream>>>(qkv, vtb);
  attn_kernel<<<dim3(SS / QBLK, BB * NH), 256, 0, stream>>>(qkv, vtb, attn);
  gemm_bt<1><<<dim3((ROWS / 128) * (MODEL_DIM / 128)), 256, 0, stream>>>(attn, wob, out, ROWS, MODEL_DIM, MODEL_DIM);
}

// Round 9
// 972.187 us; speedup vs baseline: 1.2699x; 1.0046x over previous
//
#include <hip/hip_runtime.h>
#include <hip/hip_bf16.h>
#include <stdint.h>

#define MODEL_DIM 4096
#define HEAD_DIM  128
#define NH        32
#define NKV       8
#define BB        2
#define SS        2048
#define ROWS      (BB*SS)                        // 4096
#define QKVN      (MODEL_DIM + 2*NKV*HEAD_DIM)   // 6144
#define KOFF      MODEL_DIM                      // 4096
#define VOFF      (MODEL_DIM + NKV*HEAD_DIM)     // 5120
#define SCALE_QK  0.08838834764831845f           // 1/sqrt(128)
#define SCALE_E2  0.12753102198681652f           // SCALE_QK * log2(e): exp2 domain

typedef __attribute__((ext_vector_type(8))) short short8;
typedef __attribute__((ext_vector_type(4))) float f32x4;

static __device__ __forceinline__ unsigned short f2bf(float f) {
  union { float f; unsigned u; } v; v.f = f;
  unsigned r = v.u + 0x7fffu + ((v.u >> 16) & 1u);   // round-to-nearest-even
  return (unsigned short)(r >> 16);
}
static __device__ __forceinline__ float bf2f(unsigned short u) {
  union { unsigned u; float f; } v; v.u = ((unsigned)u) << 16;
  return v.f;
}
static __device__ __forceinline__ void glds16(const unsigned short* g, const unsigned short* l) {
  __builtin_amdgcn_global_load_lds((const __attribute__((address_space(1))) void*)g,
      (__attribute__((address_space(3))) void*)l, 16, 0, 0);
}

// ---------------------------------------------------------------- converts
__global__ void cvt_bf16(const float* __restrict__ s, unsigned short* __restrict__ d, int n4) {
  int i = blockIdx.x * blockDim.x + threadIdx.x;
  int st = gridDim.x * blockDim.x;
  for (; i < n4; i += st) {
    float4 v = reinterpret_cast<const float4*>(s)[i];
    ushort4 o;
    o.x = f2bf(v.x); o.y = f2bf(v.y); o.z = f2bf(v.z); o.w = f2bf(v.w);
    reinterpret_cast<ushort4*>(d)[i] = o;
  }
}

// ---------------------------------------------------------------- GEMM  C = A * B^T
// 256x256 tile, BK=64, 8 waves (2x4), counted-vmcnt pipeline (T3+T4), LDS
// XOR-swizzle slot^=row&7 on staging source + reads (T2), setprio around
// MFMA clusters (T5), bijective XCD swizzle (T1). Per-wave vmcnt ledger:
// steady state 16 outstanding -> wait vmcnt(8) -> issue 8 more.
template<int OUT_F32>
__global__ __launch_bounds__(512, 2) void gemm_bt8(
    const unsigned short* __restrict__ A, const unsigned short* __restrict__ B,
    void* __restrict__ Cv, int M, int N, int K)
{
  __shared__ unsigned short Asl[2][256 * 64];    // 64 KiB
  __shared__ unsigned short Bsl[2][256 * 64];    // 64 KiB
  const int tid  = threadIdx.x;
  const int lane = tid & 63;
  const int w    = tid >> 6;
  const int wr   = w >> 2, wc = w & 3;           // wave -> 128x64 output sub-tile

  // T1: bijective XCD swizzle (grids here are % 8 == 0)
  const int nwg = gridDim.x, bid = blockIdx.x;
  const int q8  = nwg >> 3;
  const int wg  = (bid & 7) * q8 + (bid >> 3);
  const int gm  = M >> 8;
  const int bm  = wg % gm, bn = wg / gm;
  const int m0  = bm << 8, n0 = bn << 8;

  const int fr = lane & 15, fg = lane >> 4;

  // staging constants: issue i covers rows i*64 + w*8 + (lane>>3), slot lane&7
  const int srow  = lane >> 3;
  const int sslot = (lane & 7) ^ srow;           // pre-swizzled source slot (row&7 == srow)

  const unsigned short* Ag0 = A + (size_t)(m0 + w * 8 + srow) * K + sslot * 8;
  const unsigned short* Bg0 = B + (size_t)(n0 + w * 8 + srow) * K + sslot * 8;

  f32x4 acc[8][4] = {};
  const int nt = K >> 6;

#define STAGE_TILE(kt, buf)                                                   \
  {                                                                           \
    _Pragma("unroll")                                                         \
    for (int i = 0; i < 4; ++i) {                                             \
      glds16(Ag0 + (size_t)(i * 64) * K + (kt) * 64, &Asl[buf][(i*64 + w*8) * 64]); \
      glds16(Bg0 + (size_t)(i * 64) * K + (kt) * 64, &Bsl[buf][(i*64 + w*8) * 64]); \
    }                                                                         \
  }

  // prologue: tiles 0 and 1 in flight (16 loads/wave)
  STAGE_TILE(0, 0)
  STAGE_TILE(1, 1)

  for (int t = 0; t < nt; ++t) {
    const int cur = t & 1;
    // T4: counted wait — tile t's 8 loads are the oldest; keep t+1's in flight
    if (t + 1 < nt) asm volatile("s_waitcnt vmcnt(8)" ::: "memory");
    else            asm volatile("s_waitcnt vmcnt(0)" ::: "memory");
    __builtin_amdgcn_s_barrier();
    __builtin_amdgcn_sched_barrier(0);           // nothing crosses the data-ready point

    short8 af[8], bfv[8];
    // ---- P0: read A m-frags 0-3 (8x b128) + B n-frags 0-1 (4x b128)
    #pragma unroll
    for (int mf = 0; mf < 4; ++mf)
      #pragma unroll
      for (int kk = 0; kk < 2; ++kk) {
        const int row = wr * 128 + mf * 16 + fr;
        af[mf*2+kk] = *(const short8*)&Asl[cur][row * 64 + ((kk*4 + fg) ^ (row & 7)) * 8];
      }
    #pragma unroll
    for (int nf = 0; nf < 2; ++nf)
      #pragma unroll
      for (int kk = 0; kk < 2; ++kk) {
        const int row = wc * 64 + nf * 16 + fr;
        bfv[nf*2+kk] = *(const short8*)&Bsl[cur][row * 64 + ((kk*4 + fg) ^ (row & 7)) * 8];
      }
    __builtin_amdgcn_s_barrier();
    __builtin_amdgcn_s_setprio(1);
    #pragma unroll
    for (int mf = 0; mf < 4; ++mf)
      #pragma unroll
      for (int nf = 0; nf < 2; ++nf)
        #pragma unroll
        for (int kk = 0; kk < 2; ++kk)
          acc[mf][nf] = __builtin_amdgcn_mfma_f32_16x16x32_bf16(af[mf*2+kk], bfv[nf*2+kk], acc[mf][nf], 0, 0, 0);
    __builtin_amdgcn_s_setprio(0);
    __builtin_amdgcn_s_barrier();

    // ---- P1: read B n-frags 2-3
    #pragma unroll
    for (int nf = 0; nf < 2; ++nf)
      #pragma unroll
      for (int kk = 0; kk < 2; ++kk) {
        const int row = wc * 64 + (2 + nf) * 16 + fr;
        bfv[4 + nf*2+kk] = *(const short8*)&Bsl[cur][row * 64 + ((kk*4 + fg) ^ (row & 7)) * 8];
      }
    __builtin_amdgcn_s_barrier();
    __builtin_amdgcn_s_setprio(1);
    #pragma unroll
    for (int mf = 0; mf < 4; ++mf)
      #pragma unroll
      for (int nf = 0; nf < 2; ++nf)
        #pragma unroll
        for (int kk = 0; kk < 2; ++kk)
          acc[mf][2+nf] = __builtin_amdgcn_mfma_f32_16x16x32_bf16(af[mf*2+kk], bfv[4+nf*2+kk], acc[mf][2+nf], 0, 0, 0);
    __builtin_amdgcn_s_setprio(0);
    __builtin_amdgcn_s_barrier();

    // ---- P2: read A m-frags 4-7 (overwrite af)
    #pragma unroll
    for (int mf = 0; mf < 4; ++mf)
      #pragma unroll
      for (int kk = 0; kk < 2; ++kk) {
        const int row = wr * 128 + (4 + mf) * 16 + fr;
        af[mf*2+kk] = *(const short8*)&Asl[cur][row * 64 + ((kk*4 + fg) ^ (row & 7)) * 8];
      }
    __builtin_amdgcn_s_barrier();
    __builtin_amdgcn_s_setprio(1);
    #pragma unroll
    for (int mf = 0; mf < 4; ++mf)
      #pragma unroll
      for (int nf = 0; nf < 2; ++nf)
        #pragma unroll
        for (int kk = 0; kk < 2; ++kk)
          acc[4+mf][nf] = __builtin_amdgcn_mfma_f32_16x16x32_bf16(af[mf*2+kk], bfv[nf*2+kk], acc[4+mf][nf], 0, 0, 0);
    __builtin_amdgcn_s_setprio(0);
    __builtin_amdgcn_s_barrier();

    // ---- P3: no reads; MFMA quadrant (1,1)
    __builtin_amdgcn_s_setprio(1);
    #pragma unroll
    for (int mf = 0; mf < 4; ++mf)
      #pragma unroll
      for (int nf = 0; nf < 2; ++nf)
        #pragma unroll
        for (int kk = 0; kk < 2; ++kk)
          acc[4+mf][2+nf] = __builtin_amdgcn_mfma_f32_16x16x32_bf16(af[mf*2+kk], bfv[4+nf*2+kk], acc[4+mf][2+nf], 0, 0, 0);
    __builtin_amdgcn_s_setprio(0);
    __builtin_amdgcn_s_barrier();                // all waves done reading buf[cur]
    __builtin_amdgcn_sched_barrier(0);

    if (t + 2 < nt) STAGE_TILE(t + 2, cur)       // refill freed buffer; +8 in flight
  }

  // epilogue: C/D layout row=(lane>>4)*4+e, col=lane&15 (m89-verified)
  const int crow0 = m0 + wr * 128 + fg * 4;
  const int ccol0 = n0 + wc * 64 + fr;
  #pragma unroll
  for (int mf = 0; mf < 8; ++mf)
    #pragma unroll
    for (int nf = 0; nf < 4; ++nf) {
      const int gr = crow0 + mf * 16;
      const int gc = ccol0 + nf * 16;
      #pragma unroll
      for (int e = 0; e < 4; ++e) {
        const float v = acc[mf][nf][e];
        if (OUT_F32) ((float*)Cv)[(size_t)(gr + e) * N + gc] = v;
        else ((unsigned short*)Cv)[(size_t)(gr + e) * N + gc] = f2bf(v);
      }
    }
#undef STAGE_TILE
}

// ---------------------------------------------------------------- RoPE (in-place, Q + K)
__global__ void rope_kernel(unsigned short* __restrict__ qkv, const int* __restrict__ posp) {
  const int row = blockIdx.x;
  const float t = (float)((row & (SS - 1)) + posp[0]);
  const float c0 = -13.28771237954945f / 64.0f;     // -log2(10000)/64
  for (int i = threadIdx.x; i < (NH + NKV) * 64; i += blockDim.x) {
    const int hh = i >> 6, p = i & 63;
    const int colbase = (hh < NH) ? hh * HEAD_DIM : KOFF + (hh - NH) * HEAD_DIM;
    const float inv = exp2f((float)p * c0);
    float sn, cs;
    sincosf(t * inv, &sn, &cs);
    const size_t base = (size_t)row * QKVN + colbase + 2 * p;
    const float x1 = bf2f(qkv[base]), x2 = bf2f(qkv[base + 1]);
    qkv[base]     = f2bf(x1 * cs - x2 * sn);
    qkv[base + 1] = f2bf(x1 * sn + x2 * cs);
  }
}

// ---------------------------------------------------------------- V transpose: vt[bk][d=128][s=2048]
// Columns within each 64-block are stored in PV-slot order: position kv' holds
// actual kv = sigma(kv') = (kv'&0x23) | ((kv'&4)<<2) | ((kv'&0x18)>>1),
// matching the register layout of the swapped-QK P fragments (see attn_kernel).
// LDS tile [64 s][128 d], 16B-slot XOR swizzle by (s>>3)&7 on low-3 slot bits.
__global__ __launch_bounds__(256) void vtrans_kernel(
    const unsigned short* __restrict__ qkv, unsigned short* __restrict__ vt)
{
  __shared__ unsigned short T[64 * 128];
  const int tid = threadIdx.x;
  const int bk  = blockIdx.y;                  // b*NKV + kvh
  const int s0  = blockIdx.x * 64;
  const int b   = bk >> 3, kvh = bk & 7;

  #pragma unroll
  for (int it = 0; it < 4; ++it) {
    const int cid  = it * 256 + tid;
    const int s    = cid >> 4, slot = cid & 15;
    const int sl   = (slot & 8) | ((slot ^ (s >> 3)) & 7);
    *(uint4*)&T[s * 128 + sl * 8] =
      *(const uint4*)&qkv[(size_t)(b * SS + s0 + s) * QKVN + VOFF + kvh * HEAD_DIM + slot * 8];
  }
  __syncthreads();
  #pragma unroll
  for (int it = 0; it < 4; ++it) {
    const int cid = it * 256 + tid;
    const int d   = cid >> 3, s8 = (cid & 7) * 8;
    unsigned short tmp[8];
    #pragma unroll
    for (int j = 0; j < 8; ++j) {
      const int so   = s8 + j;                                     // PV-slot position
      const int si   = (so & 0x23) | ((so & 4) << 2) | ((so & 0x18) >> 1);  // actual kv
      const int slot = d >> 3;
      const int sl   = (slot & 8) | ((slot ^ (si >> 3)) & 7);
      tmp[j] = T[si * 128 + sl * 8 + (d & 7)];
    }
    *(uint4*)&vt[((size_t)bk * HEAD_DIM + d) * SS + s0 + s8] = *(uint4*)tmp;
  }
}

// ---------------------------------------------------------------- flash attention (causal, GQA 4:1)
// Swapped QK^T: s = mfma(K, Q) -> lane holds 16 scores for ONE q (q = lane&15,
// kv = 16ct + 4fg + e). Softmax fully in-register (2 shfl_xor per reduce);
// P feeds PV's B-operand directly (kv-slot order handled by vtrans's sigma).
#define QBLK 64
#define KVB  64

__global__ __launch_bounds__(256) void attn_kernel(
    const unsigned short* __restrict__ qkv, const unsigned short* __restrict__ vt,
    unsigned short* __restrict__ out)
{
  __shared__ unsigned short Kb[2][KVB * HEAD_DIM];      // 2 x 16 KiB
  __shared__ unsigned short Vb[2][HEAD_DIM * KVB];      // 2 x 16 KiB

  const int tid  = threadIdx.x;
  const int lane = tid & 63;
  const int w    = tid >> 6;
  const int bh   = blockIdx.y;            // b*32 + h
  const int b    = bh >> 5, h = bh & 31;
  const int kvh  = h >> 2;
  const int q0   = (gridDim.x - 1 - blockIdx.x) * QBLK;   // heavy blocks first
  const int fr   = lane & 15, fg = lane >> 4;

  const unsigned short* kg  = qkv + KOFF + kvh * HEAD_DIM;
  const unsigned short* vtg = vt + (size_t)(b * NKV + kvh) * HEAD_DIM * SS;

  // Q fragments (B-operand: col=lane&15=q, k=(lane>>4)*8+j)
  const size_t qrow0 = (size_t)(b * SS + q0 + w * 16);
  short8 qf[4];
  #pragma unroll
  for (int kk = 0; kk < 4; ++kk)
    qf[kk] = *(const short8*)&qkv[(qrow0 + fr) * QKVN + h * HEAD_DIM + kk * 32 + fg * 8];

  f32x4 ot[8] = {};                        // O^T tiles: col=q=lane&15, row d=oc*16+4fg+e
  float m_run = -INFINITY, l_run = 0.f;    // per-lane (per-q) online softmax state

  // staging lane constants
  const int krow_l = lane >> 4;                 // K: 4 rows/instr
  const int kslot  = lane & 15;
  const int vrow_l = lane >> 3;                 // Vt: 8 d-rows/instr
  const int vslot  = lane & 7;

  const int ntile = (q0 >> 6) + 1;

  // ---- prologue: stage tile 0 into buffer 0
  {
    #pragma unroll
    for (int i = 0; i < 4; ++i) {
      const int r  = w * 16 + i * 4 + krow_l;
      const int gs = (kslot & 8) | ((kslot ^ r) & 7);
      glds16(kg + (size_t)(b * SS + r) * QKVN + gs * 8, &Kb[0][(w * 16 + i * 4) * 128]);
      const int d  = w * 32 + i * 8 + vrow_l;
      const int vg = vslot ^ (d & 7);
      glds16(vtg + (size_t)d * SS + vg * 8, &Vb[0][(w * 32 + i * 8) * 64]);
    }
  }

  int cur = 0;
  for (int jt = 0; jt < ntile; ++jt) {
    __syncthreads();                       // stage(jt) landed; buf[cur^1] free
    if (jt + 1 < ntile) {                  // async prefetch next tile
      const int j0n = (jt + 1) * KVB;
      #pragma unroll
      for (int i = 0; i < 4; ++i) {
        const int r  = w * 16 + i * 4 + krow_l;
        const int gs = (kslot & 8) | ((kslot ^ r) & 7);
        glds16(kg + (size_t)(b * SS + j0n + r) * QKVN + gs * 8, &Kb[cur ^ 1][(w * 16 + i * 4) * 128]);
        const int d  = w * 32 + i * 8 + vrow_l;
        const int vg = vslot ^ (d & 7);
        glds16(vtg + (size_t)d * SS + j0n + vg * 8, &Vb[cur ^ 1][(w * 32 + i * 8) * 64]);
      }
    }
    const unsigned short* Kc = Kb[cur];
    const unsigned short* Vc = Vb[cur];
    const bool diag = (jt == ntile - 1);

    // QK^T (swapped): p[ct][e] = S^T, q = fr, kv = ct*16 + 4*fg + e; exp2 domain
    float p[4][4];
    #pragma unroll
    for (int ct = 0; ct < 4; ++ct) {
      f32x4 s = {};
      const int krow = ct * 16 + fr;
      #pragma unroll
      for (int kk = 0; kk < 4; ++kk) {
        const int c  = kk * 4 + fg;
        const int sl = (c & 8) | ((c ^ krow) & 7);
        const short8 kf = *(const short8*)&Kc[krow * 128 + sl * 8];
        s = __builtin_amdgcn_mfma_f32_16x16x32_bf16(kf, qf[kk], s, 0, 0, 0);
      }
      #pragma unroll
      for (int e = 0; e < 4; ++e) {
        float v = s[e] * SCALE_E2;
        if (diag) {
          const int kc = ct * 16 + fg * 4 + e;   // kv within tile
          const int qr = w * 16 + fr;            // q within block (j0 == q0)
          if (kc > qr) v = -INFINITY;
        }
        p[ct][e] = v;
      }
    }

    // online softmax, fully per-lane (one q per lane; fg quartet shares q)
    float mx = p[0][0];
    #pragma unroll
    for (int ct = 0; ct < 4; ++ct)
      #pragma unroll
      for (int e = 0; e < 4; ++e) mx = fmaxf(mx, p[ct][e]);
    mx = fmaxf(mx, __shfl_xor(mx, 16));
    mx = fmaxf(mx, __shfl_xor(mx, 32));
    const float nm   = fmaxf(m_run, mx);
    const float resc = exp2f(m_run - nm);
    m_run = nm;
    float sum = 0.f;
    #pragma unroll
    for (int ct = 0; ct < 4; ++ct)
      #pragma unroll
      for (int e = 0; e < 4; ++e) {
        const float pe = exp2f(p[ct][e] - nm);
        p[ct][e] = pe;
        sum += pe;
      }
    sum += __shfl_xor(sum, 16);
    sum += __shfl_xor(sum, 32);
    l_run = l_run * resc + sum;

    // pack P into PV B-fragments: slot (kk2, j) <- p[2*kk2 + (j>>2)][j&3]
    short8 pf0, pf1;
    #pragma unroll
    for (int e = 0; e < 4; ++e) {
      pf0[e]     = (short)f2bf(p[0][e]);
      pf0[e + 4] = (short)f2bf(p[1][e]);
      pf1[e]     = (short)f2bf(p[2][e]);
      pf1[e + 4] = (short)f2bf(p[3][e]);
    }

    // rescale O^T (per-lane)
    #pragma unroll
    for (int oc = 0; oc < 8; ++oc)
      #pragma unroll
      for (int e = 0; e < 4; ++e) ot[oc][e] *= resc;

    // PV (swapped): O^T[d][q] += V^T[d][kv] * P^T[kv][q]; swizzled b128 V reads.
    // Vt columns are pre-permuted (sigma) so linear slots match pf slot order.
    #pragma unroll
    for (int kk2 = 0; kk2 < 2; ++kk2) {
      const short8 pf = kk2 ? pf1 : pf0;
      #pragma unroll
      for (int oc = 0; oc < 8; ++oc) {
        const int vd = oc * 16 + fr;
        const int sl = (kk2 * 4 + fg) ^ (vd & 7);
        const short8 vf = *(const short8*)&Vc[vd * 64 + sl * 8];
        ot[oc] = __builtin_amdgcn_mfma_f32_16x16x32_bf16(vf, pf, ot[oc], 0, 0, 0);
      }
    }
    cur ^= 1;
  }

  // epilogue: divide by l (per-lane), store O
  const float invq = 1.f / l_run;
  const size_t orow = (size_t)(b * SS + q0 + w * 16) + (lane & 15);
  #pragma unroll
  for (int oc = 0; oc < 8; ++oc) {
    const unsigned short e0 = f2bf(ot[oc][0] * invq);
    const unsigned short e1 = f2bf(ot[oc][1] * invq);
    const unsigned short e2 = f2bf(ot[oc][2] * invq);
    const unsigned short e3 = f2bf(ot[oc][3] * invq);
    const uint2 val = make_uint2((unsigned)e0 | ((unsigned)e1 << 16),
                                 (unsigned)e2 | ((unsigned)e3 << 16));
    *(uint2*)&out[orow * MODEL_DIM + h * HEAD_DIM + oc * 16 + fg * 4] = val;
  }
}

// ---------------------------------------------------------------- launch
extern "C" void kernel_launch(void* const* d_in, const int* in_sizes, int n_in,
                              void* d_out, int out_size, void* d_ws, size_t ws_size,
                              hipStream_t stream) {
  const float* x  = (const float*)d_in[0];
  const float* wq = (const float*)d_in[1];
  const float* wk = (const float*)d_in[2];
  const float* wv = (const float*)d_in[3];
  const float* wo = (const float*)d_in[4];
  const int* pos  = (const int*)d_in[6];        // mask (d_in[5]) unused: causal in-kernel
  float* out = (float*)d_out;

  // workspace layout (bf16 elements), ~202 MB total
  unsigned short* xb   = (unsigned short*)d_ws;
  unsigned short* wqkv = xb   + (size_t)ROWS * MODEL_DIM;
  unsigned short* wob  = wqkv + (size_t)QKVN * MODEL_DIM;
  unsigned short* qkv  = wob  + (size_t)MODEL_DIM * MODEL_DIM;
  unsigned short* attn = qkv  + (size_t)ROWS * QKVN;
  unsigned short* vtb  = xb;   // reuse: xb is dead after gemm1 (8 MB needed of 33.5 MB)

  cvt_bf16<<<2048, 256, 0, stream>>>(x,  xb,   ROWS * MODEL_DIM / 4);
  cvt_bf16<<<2048, 256, 0, stream>>>(wq, wqkv, MODEL_DIM * MODEL_DIM / 4);
  cvt_bf16<<<1024, 256, 0, stream>>>(wk, wqkv + (size_t)MODEL_DIM * MODEL_DIM,          NKV * HEAD_DIM * MODEL_DIM / 4);
  cvt_bf16<<<1024, 256, 0, stream>>>(wv, wqkv + (size_t)(MODEL_DIM + NKV * HEAD_DIM) * MODEL_DIM, NKV * HEAD_DIM * MODEL_DIM / 4);
  cvt_bf16<<<2048, 256, 0, stream>>>(wo, wob,  MODEL_DIM * MODEL_DIM / 4);

  gemm_bt8<0><<<dim3((ROWS / 256) * (QKVN / 256)), 512, 0, stream>>>(xb, wqkv, qkv, ROWS, QKVN, MODEL_DIM);
  rope_kernel<<<ROWS, 256, 0, stream>>>(qkv, pos);
  vtrans_kernel<<<dim3(SS / 64, BB * NKV), 256, 0, stream>>>(qkv, vtb);
  attn_kernel<<<dim3(SS / QBLK, BB * NH), 256, 0, stream>>>(qkv, vtb, attn);
  gemm_bt8<1><<<dim3((ROWS / 256) * (MODEL_DIM / 256)), 512, 0, stream>>>(attn, wob, out, ROWS, MODEL_DIM, MODEL_DIM);
}